// Round 5
// baseline (1512.048 us; speedup 1.0000x reference)
//
#include <hip/hip_runtime.h>
#include <hip/hip_fp16.h>

static constexpr int BLK  = 256;   // generic block size
static constexpr int B1   = 256;   // partition blocks for hist/scatter
static constexpr int BLKW = 1024;  // threads for hist/scatter blocks
static constexpr int RSH  = 9;     // rows per bucket = 512
static constexpr int RMSK = 511;
static constexpr int NBMAX = 2048;

// --- detect whether edgeij_pair is int64 (expected) or int32 (JAX x64 off) ---
__global__ void detect_kernel(const unsigned long long* __restrict__ rc,
                              int* __restrict__ flag) {
    if (blockIdx.x == 0 && threadIdx.x == 0) {
        int is64 = 1;
        for (int i = 0; i < 8; ++i)
            if (rc[i] >= (1ull << 20)) is64 = 0;
        *flag = is64;
    }
}

// --- pass 1a: per-block LDS histogram of row>>RSH -> hist[bin*B1 + blk] ---
__global__ void hist1_kernel(const void* __restrict__ rcv,
                             const int* __restrict__ flag,
                             unsigned int* __restrict__ hist, int ne, int nb) {
    __shared__ unsigned int lh[NBMAX];
    const int b = blockIdx.x;
    const int chunk = (ne + B1 - 1) / B1;
    const int s = b * chunk, e = min(ne, s + chunk);
    for (int i = threadIdx.x; i < NBMAX; i += BLKW) lh[i] = 0u;
    __syncthreads();
    const int is64 = *flag;
    const unsigned long long* r64 = (const unsigned long long*)rcv;
    const unsigned int*       r32 = (const unsigned int*)rcv;
    for (int i = s + threadIdx.x; i < e; i += BLKW) {
        unsigned int row = is64 ? (unsigned int)r64[i] : r32[i];
        atomicAdd(&lh[row >> RSH], 1u);
    }
    __syncthreads();
    for (int i = threadIdx.x; i < nb; i += BLKW)
        hist[(size_t)i * B1 + b] = lh[i];
}

// --- generic scan: per-block exclusive scan (in-place), totals to part ---
__global__ void scan1_kernel(unsigned int* __restrict__ data,
                             unsigned int* __restrict__ part, int n) {
    __shared__ unsigned int s[BLK];
    int t = threadIdx.x;
    int i = blockIdx.x * BLK + t;
    unsigned int v = (i < n) ? data[i] : 0u;
    s[t] = v;
    __syncthreads();
    for (int off = 1; off < BLK; off <<= 1) {
        unsigned int u = (t >= off) ? s[t - off] : 0u;
        __syncthreads();
        s[t] += u;
        __syncthreads();
    }
    if (i < n) data[i] = s[t] - v;
    if (t == BLK - 1) part[blockIdx.x] = s[t];
}

__global__ void scan2_kernel(unsigned int* __restrict__ part, int np) {
    __shared__ unsigned int s[BLK];
    __shared__ unsigned int carry_s;
    int t = threadIdx.x;
    if (t == 0) carry_s = 0u;
    __syncthreads();
    for (int base = 0; base < np; base += BLK) {
        int i = base + t;
        unsigned int v = (i < np) ? part[i] : 0u;
        s[t] = v;
        __syncthreads();
        for (int off = 1; off < BLK; off <<= 1) {
            unsigned int u = (t >= off) ? s[t - off] : 0u;
            __syncthreads();
            s[t] += u;
            __syncthreads();
        }
        unsigned int carry = carry_s;
        if (i < np) part[i] = s[t] - v + carry;
        __syncthreads();
        if (t == BLK - 1) carry_s = carry + s[t];
        __syncthreads();
    }
}

__global__ void scan3_kernel(unsigned int* __restrict__ data,
                             const unsigned int* __restrict__ part, int n) {
    int i = blockIdx.x * BLK + threadIdx.x;
    if (i < n) data[i] += part[blockIdx.x];
}

// --- pass 1b: scatter edges into bucket runs; pack (row:20|col:20|a:f16) ---
__global__ void scatter1_kernel(const void* __restrict__ rcv,
                                const float2* __restrict__ eattr,
                                const int* __restrict__ flag,
                                const unsigned int* __restrict__ base,
                                unsigned long long* __restrict__ edges,
                                int ne, int nb) {
    __shared__ unsigned int cur[NBMAX];
    const int b = blockIdx.x;
    const int chunk = (ne + B1 - 1) / B1;
    const int s = b * chunk, e = min(ne, s + chunk);
    for (int i = threadIdx.x; i < nb; i += BLKW)
        cur[i] = base[(size_t)i * B1 + b];
    __syncthreads();
    const int is64 = *flag;
    const unsigned long long* r64 = (const unsigned long long*)rcv;
    const unsigned int*       r32 = (const unsigned int*)rcv;
    for (int i = s + threadIdx.x; i < e; i += BLKW) {
        unsigned long long row, col;
        if (is64) { row = r64[i]; col = r64[(size_t)ne + i]; }
        else      { row = r32[i]; col = r32[(size_t)ne + i]; }
        float a = eattr[i].x;
        unsigned short h = __half_as_ushort(__float2half(a));
        unsigned long long q = (row << 44) | (col << 24) | (unsigned long long)h;
        unsigned int pos = atomicAdd(&cur[(unsigned int)(row >> RSH)], 1u);
        edges[pos] = q;
    }
}

// --- vertex preprocessing: wbA = w*b/A, wA = w/A, x0 ---
__global__ void vprep_kernel(const float* __restrict__ vattr,
                             const float* __restrict__ g,
                             float2* __restrict__ vp,
                             float* __restrict__ x0, int nv) {
    int i = blockIdx.x * BLK + threadIdx.x;
    if (i >= nv) return;
    float A = vattr[3 * i + 0];
    float b = vattr[3 * i + 1];
    float x = vattr[3 * i + 2];
    float w = g[0];
    vp[i] = make_float2(w * b / A, w / A);
    x0[i] = x;
}

__device__ __forceinline__ void edge_accum(unsigned long long q,
                                           const float* __restrict__ xin,
                                           float* acc) {
    float a = __half2float(__ushort_as_half((unsigned short)(q & 0xFFFFu)));
    unsigned int col = (unsigned int)(q >> 24) & 0xFFFFFu;
    unsigned int rlo = (unsigned int)(q >> 44) & RMSK;
    atomicAdd(&acc[rlo], a * xin[col]);   // ds_add_f32, no return
}

// --- fused Jacobi iteration: block b owns rows [b*512, b*512+512) ---
__global__ void iter_kernel(const unsigned int* __restrict__ bbase,  // hist, stride B1
                            const unsigned long long* __restrict__ edges,
                            const float2* __restrict__ vp,
                            const float* __restrict__ xin,
                            float* __restrict__ xout,
                            int nv, int ne, int nb) {
    __shared__ float acc[512];
    const int b = blockIdx.x;
    const int t = threadIdx.x;
    for (int i = t; i < 512; i += BLK) acc[i] = 0.0f;
    __syncthreads();
    const unsigned int s = bbase[(size_t)b * B1];
    const unsigned int e = (b == nb - 1) ? (unsigned int)ne
                                         : bbase[(size_t)(b + 1) * B1];
    unsigned int j = s + t;
    // 8-deep software pipeline: 8 independent edge loads, then 8 gathers
    for (; j + 7u * BLK < e; j += 8u * BLK) {
        unsigned long long q0 = __builtin_nontemporal_load(&edges[j + 0u * BLK]);
        unsigned long long q1 = __builtin_nontemporal_load(&edges[j + 1u * BLK]);
        unsigned long long q2 = __builtin_nontemporal_load(&edges[j + 2u * BLK]);
        unsigned long long q3 = __builtin_nontemporal_load(&edges[j + 3u * BLK]);
        unsigned long long q4 = __builtin_nontemporal_load(&edges[j + 4u * BLK]);
        unsigned long long q5 = __builtin_nontemporal_load(&edges[j + 5u * BLK]);
        unsigned long long q6 = __builtin_nontemporal_load(&edges[j + 6u * BLK]);
        unsigned long long q7 = __builtin_nontemporal_load(&edges[j + 7u * BLK]);
        edge_accum(q0, xin, acc);
        edge_accum(q1, xin, acc);
        edge_accum(q2, xin, acc);
        edge_accum(q3, xin, acc);
        edge_accum(q4, xin, acc);
        edge_accum(q5, xin, acc);
        edge_accum(q6, xin, acc);
        edge_accum(q7, xin, acc);
    }
    for (; j < e; j += BLK) {
        unsigned long long q = __builtin_nontemporal_load(&edges[j]);
        edge_accum(q, xin, acc);
    }
    __syncthreads();
    const int r0 = b << RSH;
    for (int i = t; i < 512; i += BLK) {
        int r = r0 + i;
        if (r < nv) {
            float2 qv = vp[r];
            __builtin_nontemporal_store(xin[r] + qv.x - qv.y * acc[i], &xout[r]);
        }
    }
}

extern "C" void kernel_launch(void* const* d_in, const int* in_sizes, int n_in,
                              void* d_out, int out_size, void* d_ws, size_t ws_size,
                              hipStream_t stream) {
    const float* vattr = (const float*)d_in[1];
    const void*  eij   = (const void*)d_in[2];
    const float* eattr = (const float*)d_in[3];
    const float* g     = (const float*)d_in[4];
    const int nv = in_sizes[1] / 3;   // 1,000,000
    const int ne = in_sizes[3] / 2;   // 16,000,000
    const int n_iters = 10;
    const int nb = (nv + RMSK) >> RSH;        // 1954 buckets of 512 rows
    const int nh = nb * B1;                   // hist/scan length (~500K)

    // workspace layout
    char* ws = (char*)d_ws;
    size_t off = 0;
    auto alloc = [&](size_t bytes) -> void* {
        void* p = ws + off;
        off = (off + bytes + 255) & ~(size_t)255;
        return p;
    };
    unsigned long long* edges = (unsigned long long*)alloc((size_t)ne * 8); // 128MB
    unsigned int* hist = (unsigned int*)alloc((size_t)nh * 4);              // ~2MB
    unsigned int* part = (unsigned int*)alloc(((size_t)(nh + BLK - 1) / BLK) * 4);
    float2* vp = (float2*)alloc((size_t)nv * 8);
    float*  xa = (float*) alloc((size_t)nv * 4);
    float*  xb = (float*) alloc((size_t)nv * 4);
    int*  flag = (int*)   alloc(256);

    const int vblocks = (nv + BLK - 1) / BLK;
    const int sblocks = (nh + BLK - 1) / BLK;

    detect_kernel<<<1, 64, 0, stream>>>((const unsigned long long*)eij, flag);
    hist1_kernel<<<B1, BLKW, 0, stream>>>(eij, flag, hist, ne, nb);
    scan1_kernel<<<sblocks, BLK, 0, stream>>>(hist, part, nh);
    scan2_kernel<<<1, BLK, 0, stream>>>(part, sblocks);
    scan3_kernel<<<sblocks, BLK, 0, stream>>>(hist, part, nh);
    scatter1_kernel<<<B1, BLKW, 0, stream>>>(eij, (const float2*)eattr, flag,
                                             hist, edges, ne, nb);
    vprep_kernel<<<vblocks, BLK, 0, stream>>>(vattr, g, vp, xa, nv);

    float* xin  = xa;
    float* xout = xb;
    for (int it = 0; it < n_iters; ++it) {
        float* dst = (it == n_iters - 1) ? (float*)d_out : xout;
        iter_kernel<<<nb, BLK, 0, stream>>>(hist, edges, vp, xin, dst,
                                            nv, ne, nb);
        float* t = xin; xin = dst; xout = t;
    }
}

// Round 6
// 1447.144 us; speedup vs baseline: 1.0448x; 1.0448x over previous
//
#include <hip/hip_runtime.h>
#include <hip/hip_fp16.h>

static constexpr int BLK  = 256;   // generic block size
static constexpr int B1   = 256;   // partition blocks for hist/scatter
static constexpr int BLKW = 1024;  // threads for hist/scatter/colsort/iter blocks
static constexpr int RSH  = 13;    // rows per bucket = 8192
static constexpr int RPB  = 8192;
static constexpr int RMSK = 8191;
static constexpr int NBMAX = 128;  // >= 123 buckets

typedef unsigned long long ull;

// --- detect whether edgeij_pair is int64 (expected) or int32 (JAX x64 off) ---
__global__ void detect_kernel(const ull* __restrict__ rc, int* __restrict__ flag) {
    if (blockIdx.x == 0 && threadIdx.x == 0) {
        int is64 = 1;
        for (int i = 0; i < 8; ++i)
            if (rc[i] >= (1ull << 20)) is64 = 0;
        *flag = is64;
    }
}

// --- pass 1a: per-block LDS histogram of row>>RSH -> hist[bin*B1 + blk] ---
__global__ void hist1_kernel(const void* __restrict__ rcv,
                             const int* __restrict__ flag,
                             unsigned int* __restrict__ hist, int ne, int nb) {
    __shared__ unsigned int lh[NBMAX];
    const int b = blockIdx.x;
    const int chunk = (ne + B1 - 1) / B1;
    const int s = b * chunk, e = min(ne, s + chunk);
    for (int i = threadIdx.x; i < NBMAX; i += BLKW) lh[i] = 0u;
    __syncthreads();
    const int is64 = *flag;
    const ull*          r64 = (const ull*)rcv;
    const unsigned int* r32 = (const unsigned int*)rcv;
    for (int i = s + threadIdx.x; i < e; i += BLKW) {
        unsigned int row = is64 ? (unsigned int)r64[i] : r32[i];
        atomicAdd(&lh[row >> RSH], 1u);
    }
    __syncthreads();
    for (int i = threadIdx.x; i < nb; i += BLKW)
        hist[(size_t)i * B1 + b] = lh[i];
}

// --- generic scan: per-block exclusive scan (in-place), totals to part ---
__global__ void scan1_kernel(unsigned int* __restrict__ data,
                             unsigned int* __restrict__ part, int n) {
    __shared__ unsigned int s[BLK];
    int t = threadIdx.x;
    int i = blockIdx.x * BLK + t;
    unsigned int v = (i < n) ? data[i] : 0u;
    s[t] = v;
    __syncthreads();
    for (int off = 1; off < BLK; off <<= 1) {
        unsigned int u = (t >= off) ? s[t - off] : 0u;
        __syncthreads();
        s[t] += u;
        __syncthreads();
    }
    if (i < n) data[i] = s[t] - v;
    if (t == BLK - 1) part[blockIdx.x] = s[t];
}

__global__ void scan2_kernel(unsigned int* __restrict__ part, int np) {
    __shared__ unsigned int s[BLK];
    __shared__ unsigned int carry_s;
    int t = threadIdx.x;
    if (t == 0) carry_s = 0u;
    __syncthreads();
    for (int base = 0; base < np; base += BLK) {
        int i = base + t;
        unsigned int v = (i < np) ? part[i] : 0u;
        s[t] = v;
        __syncthreads();
        for (int off = 1; off < BLK; off <<= 1) {
            unsigned int u = (t >= off) ? s[t - off] : 0u;
            __syncthreads();
            s[t] += u;
            __syncthreads();
        }
        unsigned int carry = carry_s;
        if (i < np) part[i] = s[t] - v + carry;
        __syncthreads();
        if (t == BLK - 1) carry_s = carry + s[t];
        __syncthreads();
    }
}

__global__ void scan3_kernel(unsigned int* __restrict__ data,
                             const unsigned int* __restrict__ part, int n) {
    int i = blockIdx.x * BLK + threadIdx.x;
    if (i < n) data[i] += part[blockIdx.x];
}

// --- pass 1b: scatter edges into coarse bucket runs; pack (row:20|col:20|a:f16) ---
__global__ void scatter1_kernel(const void* __restrict__ rcv,
                                const float2* __restrict__ eattr,
                                const int* __restrict__ flag,
                                const unsigned int* __restrict__ base,
                                ull* __restrict__ edges, int ne, int nb) {
    __shared__ unsigned int cur[NBMAX];
    const int b = blockIdx.x;
    const int chunk = (ne + B1 - 1) / B1;
    const int s = b * chunk, e = min(ne, s + chunk);
    for (int i = threadIdx.x; i < nb; i += BLKW)
        cur[i] = base[(size_t)i * B1 + b];
    __syncthreads();
    const int is64 = *flag;
    const ull*          r64 = (const ull*)rcv;
    const unsigned int* r32 = (const unsigned int*)rcv;
    for (int i = s + threadIdx.x; i < e; i += BLKW) {
        ull row, col;
        if (is64) { row = r64[i]; col = r64[(size_t)ne + i]; }
        else      { row = r32[i]; col = r32[(size_t)ne + i]; }
        float a = eattr[i].x;
        unsigned short h = __half_as_ushort(__float2half(a));
        ull q = (row << 44) | (col << 24) | (ull)h;
        unsigned int pos = atomicAdd(&cur[(unsigned int)(row >> RSH)], 1u);
        edges[pos] = q;
    }
}

// --- pass 2: per-bucket counting sort by col>>10 (approximate col order) ---
// one block per bucket; emits col-binned edges + the bucket's col-midpoint.
__global__ void colsort_kernel(const ull* __restrict__ edges,
                               const unsigned int* __restrict__ base,
                               ull* __restrict__ edges2,
                               unsigned int* __restrict__ mid, int ne, int nb) {
    __shared__ unsigned int bins[1024];
    __shared__ unsigned int cur[1024];
    const int b = blockIdx.x;
    const int t = threadIdx.x;
    const unsigned int s = base[(size_t)b * B1];
    const unsigned int e = (b == nb - 1) ? (unsigned int)ne
                                         : base[(size_t)(b + 1) * B1];
    bins[t] = 0u;
    __syncthreads();
    for (unsigned int j = s + t; j < e; j += BLKW) {
        ull q = edges[j];
        atomicAdd(&bins[(unsigned int)(q >> 34) & 1023u], 1u);
    }
    __syncthreads();
    unsigned int v = bins[t];
    for (int off = 1; off < 1024; off <<= 1) {
        unsigned int u = (t >= off) ? bins[t - off] : 0u;
        __syncthreads();
        bins[t] += u;
        __syncthreads();
    }
    unsigned int excl = bins[t] - v;   // exclusive scan value
    cur[t] = excl;
    if (t == 512) mid[b] = s + excl;   // col-space midpoint (col >= 524288)
    __syncthreads();
    for (unsigned int j = s + t; j < e; j += BLKW) {
        ull q = edges[j];
        unsigned int pos = atomicAdd(&cur[(unsigned int)(q >> 34) & 1023u], 1u);
        edges2[s + pos] = q;
    }
}

// --- vertex preprocessing: wbA = w*b/A, wA = w/A, x0 ---
__global__ void vprep_kernel(const float* __restrict__ vattr,
                             const float* __restrict__ g,
                             float2* __restrict__ vp,
                             float* __restrict__ x0, int nv) {
    int i = blockIdx.x * BLK + threadIdx.x;
    if (i >= nv) return;
    float A = vattr[3 * i + 0];
    float b = vattr[3 * i + 1];
    float x = vattr[3 * i + 2];
    float w = g[0];
    vp[i] = make_float2(w * b / A, w / A);
    x0[i] = x;
}

// --- iteration phase A: block (b, half) accumulates its col-half into acc,
//     then flushes the 8192-row partial to p0/p1 (dense 4MB arrays). ---
__global__ __launch_bounds__(BLKW)
void iter_kernel(const unsigned int* __restrict__ base,
                 const unsigned int* __restrict__ mid,
                 const ull* __restrict__ edges2,
                 const float* __restrict__ xin,
                 float* __restrict__ p0, float* __restrict__ p1,
                 int ne, int nb) {
    __shared__ float acc[RPB];
    const int blk = blockIdx.x;
    const int b = blk >> 1, half = blk & 1;
    const int t = threadIdx.x;
    #pragma unroll
    for (int i = t; i < RPB; i += BLKW) acc[i] = 0.0f;
    __syncthreads();
    const unsigned int s0 = base[(size_t)b * B1];
    const unsigned int e0 = (b == nb - 1) ? (unsigned int)ne
                                          : base[(size_t)(b + 1) * B1];
    const unsigned int m = mid[b];
    const unsigned int s = half ? m : s0;
    const unsigned int e = half ? e0 : m;
    #pragma unroll 4
    for (unsigned int j = s + t; j < e; j += BLKW) {
        ull q = edges2[j];
        float a = __half2float(__ushort_as_half((unsigned short)(q & 0xFFFFu)));
        unsigned int col = (unsigned int)(q >> 24) & 0xFFFFFu;
        unsigned int r   = (unsigned int)(q >> 44) & RMSK;
        atomicAdd(&acc[r], a * xin[col]);   // ds_add_f32, no return
    }
    __syncthreads();
    float* p = half ? p1 : p0;
    const size_t r0 = (size_t)b << RSH;
    #pragma unroll
    for (int i = t; i < RPB; i += BLKW) p[r0 + i] = acc[i];
}

// --- iteration phase B: merge halves + Jacobi update ---
__global__ void merge_kernel(const float* __restrict__ p0,
                             const float* __restrict__ p1,
                             const float2* __restrict__ vp,
                             const float* __restrict__ xin,
                             float* __restrict__ xout, int nv) {
    int i = blockIdx.x * BLK + threadIdx.x;
    if (i >= nv) return;
    float c = p0[i] + p1[i];
    float2 q = vp[i];
    xout[i] = xin[i] + q.x - q.y * c;
}

extern "C" void kernel_launch(void* const* d_in, const int* in_sizes, int n_in,
                              void* d_out, int out_size, void* d_ws, size_t ws_size,
                              hipStream_t stream) {
    const float* vattr = (const float*)d_in[1];
    const void*  eij   = (const void*)d_in[2];
    const float* eattr = (const float*)d_in[3];
    const float* g     = (const float*)d_in[4];
    const int nv = in_sizes[1] / 3;   // 1,000,000
    const int ne = in_sizes[3] / 2;   // 16,000,000
    const int n_iters = 10;
    const int nb = (nv + RMSK) >> RSH;        // 123 buckets of 8192 rows
    const int nh = nb * B1;                   // hist/scan length (~31.5K)
    const int nprows = nb << RSH;             // padded row count (1,007,616)

    // workspace layout
    char* ws = (char*)d_ws;
    size_t off = 0;
    auto alloc = [&](size_t bytes) -> void* {
        void* p = ws + off;
        off = (off + bytes + 255) & ~(size_t)255;
        return p;
    };
    ull* edges  = (ull*)alloc((size_t)ne * 8);   // 128MB (coarse-bucketed)
    ull* edges2 = (ull*)alloc((size_t)ne * 8);   // 128MB (col-sorted)
    unsigned int* hist = (unsigned int*)alloc((size_t)nh * 4);
    unsigned int* part = (unsigned int*)alloc(((size_t)(nh + BLK - 1) / BLK) * 4);
    unsigned int* mid  = (unsigned int*)alloc((size_t)nb * 4);
    float* p0 = (float*)alloc((size_t)nprows * 4);   // 4MB partials
    float* p1 = (float*)alloc((size_t)nprows * 4);
    float2* vp = (float2*)alloc((size_t)nv * 8);
    float*  xa = (float*) alloc((size_t)nv * 4);
    float*  xb = (float*) alloc((size_t)nv * 4);
    int*  flag = (int*)   alloc(256);

    const int vblocks = (nv + BLK - 1) / BLK;
    const int sblocks = (nh + BLK - 1) / BLK;

    detect_kernel<<<1, 64, 0, stream>>>((const ull*)eij, flag);
    hist1_kernel<<<B1, BLKW, 0, stream>>>(eij, flag, hist, ne, nb);
    scan1_kernel<<<sblocks, BLK, 0, stream>>>(hist, part, nh);
    scan2_kernel<<<1, BLK, 0, stream>>>(part, sblocks);
    scan3_kernel<<<sblocks, BLK, 0, stream>>>(hist, part, nh);
    scatter1_kernel<<<B1, BLKW, 0, stream>>>(eij, (const float2*)eattr, flag,
                                             hist, edges, ne, nb);
    colsort_kernel<<<nb, BLKW, 0, stream>>>(edges, hist, edges2, mid, ne, nb);
    vprep_kernel<<<vblocks, BLK, 0, stream>>>(vattr, g, vp, xa, nv);

    float* xin  = xa;
    float* xout = xb;
    for (int it = 0; it < n_iters; ++it) {
        iter_kernel<<<2 * nb, BLKW, 0, stream>>>(hist, mid, edges2, xin,
                                                 p0, p1, ne, nb);
        float* dst = (it == n_iters - 1) ? (float*)d_out : xout;
        merge_kernel<<<vblocks, BLK, 0, stream>>>(p0, p1, vp, xin, dst, nv);
        float* t = xin; xin = dst; xout = t;
    }
}

// Round 7
// 1248.227 us; speedup vs baseline: 1.2114x; 1.1594x over previous
//
#include <hip/hip_runtime.h>
#include <hip/hip_fp16.h>

static constexpr int BLK  = 256;   // generic block size
static constexpr int B1   = 256;   // partition blocks for hist/scatter
static constexpr int BLKW = 1024;  // threads for hist/scatter/iter blocks
static constexpr int RSH  = 14;    // rows per bucket = 16384
static constexpr int RPB  = 16384;
static constexpr int RMSK = 16383;
static constexpr int NCS  = 4;     // col splits
static constexpr int CSH  = 18;    // col>>18 -> 0..3
static constexpr int NSMAX = 256;  // >= 248 segments

typedef unsigned long long ull;

// --- detect whether edgeij_pair is int64 (expected) or int32 (JAX x64 off) ---
__global__ void detect_kernel(const ull* __restrict__ rc, int* __restrict__ flag) {
    if (blockIdx.x == 0 && threadIdx.x == 0) {
        int is64 = 1;
        for (int i = 0; i < 8; ++i)
            if (rc[i] >= (1ull << 20)) is64 = 0;
        *flag = is64;
    }
}

// --- hist of seg = (row>>RSH)*NCS | (col>>CSH) -> hist[seg*B1 + blk] ---
__global__ void hist1_kernel(const void* __restrict__ rcv,
                             const int* __restrict__ flag,
                             unsigned int* __restrict__ hist, int ne, int nseg) {
    __shared__ unsigned int lh[NSMAX];
    const int b = blockIdx.x;
    const int chunk = (ne + B1 - 1) / B1;
    const int s = b * chunk, e = min(ne, s + chunk);
    for (int i = threadIdx.x; i < NSMAX; i += BLKW) lh[i] = 0u;
    __syncthreads();
    const int is64 = *flag;
    const ull*          r64 = (const ull*)rcv;
    const unsigned int* r32 = (const unsigned int*)rcv;
    for (int i = s + threadIdx.x; i < e; i += BLKW) {
        unsigned int row, col;
        if (is64) { row = (unsigned int)r64[i]; col = (unsigned int)r64[(size_t)ne + i]; }
        else      { row = r32[i];               col = r32[(size_t)ne + i]; }
        unsigned int seg = (row >> RSH) * NCS + (col >> CSH);
        atomicAdd(&lh[seg], 1u);
    }
    __syncthreads();
    for (int i = threadIdx.x; i < nseg; i += BLKW)
        hist[(size_t)i * B1 + b] = lh[i];
}

// --- generic scan: per-block exclusive scan (in-place), totals to part ---
__global__ void scan1_kernel(unsigned int* __restrict__ data,
                             unsigned int* __restrict__ part, int n) {
    __shared__ unsigned int s[BLK];
    int t = threadIdx.x;
    int i = blockIdx.x * BLK + t;
    unsigned int v = (i < n) ? data[i] : 0u;
    s[t] = v;
    __syncthreads();
    for (int off = 1; off < BLK; off <<= 1) {
        unsigned int u = (t >= off) ? s[t - off] : 0u;
        __syncthreads();
        s[t] += u;
        __syncthreads();
    }
    if (i < n) data[i] = s[t] - v;
    if (t == BLK - 1) part[blockIdx.x] = s[t];
}

__global__ void scan2_kernel(unsigned int* __restrict__ part, int np) {
    __shared__ unsigned int s[BLK];
    __shared__ unsigned int carry_s;
    int t = threadIdx.x;
    if (t == 0) carry_s = 0u;
    __syncthreads();
    for (int base = 0; base < np; base += BLK) {
        int i = base + t;
        unsigned int v = (i < np) ? part[i] : 0u;
        s[t] = v;
        __syncthreads();
        for (int off = 1; off < BLK; off <<= 1) {
            unsigned int u = (t >= off) ? s[t - off] : 0u;
            __syncthreads();
            s[t] += u;
            __syncthreads();
        }
        unsigned int carry = carry_s;
        if (i < np) part[i] = s[t] - v + carry;
        __syncthreads();
        if (t == BLK - 1) carry_s = carry + s[t];
        __syncthreads();
    }
}

__global__ void scan3_kernel(unsigned int* __restrict__ data,
                             const unsigned int* __restrict__ part, int n) {
    int i = blockIdx.x * BLK + threadIdx.x;
    if (i < n) data[i] += part[blockIdx.x];
}

// --- scatter edges into (rowbucket, colsplit) segments; pack (row|col|a_f16) ---
__global__ void scatter1_kernel(const void* __restrict__ rcv,
                                const float2* __restrict__ eattr,
                                const int* __restrict__ flag,
                                const unsigned int* __restrict__ base,
                                ull* __restrict__ edges, int ne, int nseg) {
    __shared__ unsigned int cur[NSMAX];
    const int b = blockIdx.x;
    const int chunk = (ne + B1 - 1) / B1;
    const int s = b * chunk, e = min(ne, s + chunk);
    for (int i = threadIdx.x; i < nseg; i += BLKW)
        cur[i] = base[(size_t)i * B1 + b];
    __syncthreads();
    const int is64 = *flag;
    const ull*          r64 = (const ull*)rcv;
    const unsigned int* r32 = (const unsigned int*)rcv;
    for (int i = s + threadIdx.x; i < e; i += BLKW) {
        ull row, col;
        if (is64) { row = r64[i]; col = r64[(size_t)ne + i]; }
        else      { row = r32[i]; col = r32[(size_t)ne + i]; }
        float a = eattr[i].x;
        unsigned short h = __half_as_ushort(__float2half(a));
        ull q = (row << 44) | (col << 24) | (ull)h;
        unsigned int seg = (unsigned int)(row >> RSH) * NCS
                         + (unsigned int)(col >> CSH);
        unsigned int pos = atomicAdd(&cur[seg], 1u);
        edges[pos] = q;
    }
}

// --- vertex preprocessing: wbA = w*b/A, wA = w/A, x0 ---
__global__ void vprep_kernel(const float* __restrict__ vattr,
                             const float* __restrict__ g,
                             float2* __restrict__ vp,
                             float* __restrict__ x0, int nv) {
    int i = blockIdx.x * BLK + threadIdx.x;
    if (i >= nv) return;
    float A = vattr[3 * i + 0];
    float b = vattr[3 * i + 1];
    float x = vattr[3 * i + 2];
    float w = g[0];
    vp[i] = make_float2(w * b / A, w / A);
    x0[i] = x;
}

// --- iteration phase A: block = segment (b, cs). cs = blockIdx&3 is constant
//     per XCD under round-robin dispatch -> the 1MB x col-window stays L2-hot.
__global__ __launch_bounds__(BLKW)
void iter_kernel(const unsigned int* __restrict__ base,
                 const ull* __restrict__ edges,
                 const float* __restrict__ xin,
                 float* __restrict__ p,          // NCS planes of nprows floats
                 int ne, int nseg, int nprows) {
    __shared__ float acc[RPB];
    const int i = blockIdx.x;
    const int b = i >> 2, cs = i & 3;
    const int t = threadIdx.x;
    #pragma unroll
    for (int k = t; k < RPB; k += BLKW) acc[k] = 0.0f;
    __syncthreads();
    const unsigned int s = base[(size_t)i * B1];
    const unsigned int e = (i == nseg - 1) ? (unsigned int)ne
                                           : base[(size_t)(i + 1) * B1];
    #pragma unroll 4
    for (unsigned int j = s + t; j < e; j += BLKW) {
        ull q = edges[j];
        float a = __half2float(__ushort_as_half((unsigned short)(q & 0xFFFFu)));
        unsigned int col = (unsigned int)(q >> 24) & 0xFFFFFu;
        unsigned int r   = (unsigned int)(q >> 44) & RMSK;
        atomicAdd(&acc[r], a * xin[col]);   // ds_add_f32, no return
    }
    __syncthreads();
    float* plane = p + (size_t)cs * nprows + ((size_t)b << RSH);
    #pragma unroll
    for (int k = t; k < RPB; k += BLKW) plane[k] = acc[k];
}

// --- iteration phase B: merge col-split partials + Jacobi update ---
__global__ void merge_kernel(const float* __restrict__ p,
                             const float2* __restrict__ vp,
                             const float* __restrict__ xin,
                             float* __restrict__ xout, int nv, int nprows) {
    int i = blockIdx.x * BLK + threadIdx.x;
    if (i >= nv) return;
    float c = p[i] + p[(size_t)nprows + i]
            + p[2 * (size_t)nprows + i] + p[3 * (size_t)nprows + i];
    float2 q = vp[i];
    xout[i] = xin[i] + q.x - q.y * c;
}

extern "C" void kernel_launch(void* const* d_in, const int* in_sizes, int n_in,
                              void* d_out, int out_size, void* d_ws, size_t ws_size,
                              hipStream_t stream) {
    const float* vattr = (const float*)d_in[1];
    const void*  eij   = (const void*)d_in[2];
    const float* eattr = (const float*)d_in[3];
    const float* g     = (const float*)d_in[4];
    const int nv = in_sizes[1] / 3;   // 1,000,000
    const int ne = in_sizes[3] / 2;   // 16,000,000
    const int n_iters = 10;
    const int nb   = (nv + RMSK) >> RSH;      // 62 row-buckets of 16384 rows
    const int nseg = nb * NCS;                // 248 segments
    const int nh   = nseg * B1;               // 63488
    const int nprows = nb << RSH;             // padded rows (1,015,808)

    // workspace layout
    char* ws = (char*)d_ws;
    size_t off = 0;
    auto alloc = [&](size_t bytes) -> void* {
        void* p = ws + off;
        off = (off + bytes + 255) & ~(size_t)255;
        return p;
    };
    ull* edges = (ull*)alloc((size_t)ne * 8);                 // 128MB
    unsigned int* hist = (unsigned int*)alloc((size_t)nh * 4);
    unsigned int* part = (unsigned int*)alloc(((size_t)(nh + BLK - 1) / BLK) * 4);
    float* p = (float*)alloc((size_t)NCS * nprows * 4);       // ~16MB partials
    float2* vp = (float2*)alloc((size_t)nv * 8);
    float*  xa = (float*) alloc((size_t)nv * 4);
    float*  xb = (float*) alloc((size_t)nv * 4);
    int*  flag = (int*)   alloc(256);

    const int vblocks = (nv + BLK - 1) / BLK;
    const int sblocks = (nh + BLK - 1) / BLK;   // 248

    detect_kernel<<<1, 64, 0, stream>>>((const ull*)eij, flag);
    hist1_kernel<<<B1, BLKW, 0, stream>>>(eij, flag, hist, ne, nseg);
    scan1_kernel<<<sblocks, BLK, 0, stream>>>(hist, part, nh);
    scan2_kernel<<<1, BLK, 0, stream>>>(part, sblocks);
    scan3_kernel<<<sblocks, BLK, 0, stream>>>(hist, part, nh);
    scatter1_kernel<<<B1, BLKW, 0, stream>>>(eij, (const float2*)eattr, flag,
                                             hist, edges, ne, nseg);
    vprep_kernel<<<vblocks, BLK, 0, stream>>>(vattr, g, vp, xa, nv);

    float* xin  = xa;
    float* xout = xb;
    for (int it = 0; it < n_iters; ++it) {
        iter_kernel<<<nseg, BLKW, 0, stream>>>(hist, edges, xin, p, ne, nseg,
                                               nprows);
        float* dst = (it == n_iters - 1) ? (float*)d_out : xout;
        merge_kernel<<<vblocks, BLK, 0, stream>>>(p, vp, xin, dst, nv, nprows);
        float* t = xin; xin = dst; xout = t;
    }
}